// Round 2
// baseline (1229.800 us; speedup 1.0000x reference)
//
#include <hip/hip_runtime.h>
#include <hip/hip_bf16.h>

typedef unsigned int u32;
typedef __attribute__((ext_vector_type(8))) short short8;
typedef __attribute__((ext_vector_type(4))) float f32x4;

// round-to-nearest-even f32->bf16, packed pair (a in low 16, b in high 16)
__device__ __forceinline__ u32 bf16_rne(float f) {
  u32 u = __builtin_bit_cast(u32, f);
  return (u + 0x7fffu + ((u >> 16) & 1u)) >> 16;
}
__device__ __forceinline__ u32 pk_bf16(float a, float b) {
  return bf16_rne(a) | (bf16_rne(b) << 16);
}
__device__ __forceinline__ float bflo(u32 u) { return __builtin_bit_cast(float, u << 16); }
__device__ __forceinline__ float bfhi(u32 u) { return __builtin_bit_cast(float, u & 0xffff0000u); }

// ---------------------------------------------------------------------------
// Weight swizzle: W [N][K] f32 row-major  ->  bf16 frag-block order:
//   out[((k32*(N/16) + t)*64 + l)*8 + j] = W[16t + (l&15)][32*k32 + 8*(l>>4) + j]
// so a B-fragment (16x16x32 bf16 MFMA B operand) is one contiguous 1KB block:
// lane l does a single aligned ds_read_b128.
// ---------------------------------------------------------------------------
__global__ void swz_kernel(const float* __restrict__ W, unsigned short* __restrict__ out,
                           int N, int K) {
  int tid = blockIdx.x * 256 + threadIdx.x;
  if (tid >= N * K) return;
  int j = tid & 7, l = (tid >> 3) & 63, rest = tid >> 9;
  int nt = N >> 4;
  int t = rest % nt, k32 = rest / nt;
  int o = t * 16 + (l & 15);
  int k = k32 * 32 + (l >> 4) * 8 + j;
  out[tid] = (unsigned short)bf16_rne(W[(size_t)o * K + k]);
}

// ---------------------------------------------------------------------------
// aux linear part: aux[b] = x[b] . lin_w + lin_b + cin_out_b   (one wave/row)
// ---------------------------------------------------------------------------
__global__ void lin_kernel(const float* __restrict__ x, const float* __restrict__ lw,
                           const float* __restrict__ lb, const float* __restrict__ cb,
                           float* __restrict__ aux) {
  int row = blockIdx.x * 4 + (threadIdx.x >> 6);
  int lane = threadIdx.x & 63;
  const float* xr = x + (size_t)row * 1280;
  float s = 0.f;
#pragma unroll
  for (int e = 0; e < 20; ++e) s += xr[e * 64 + lane] * lw[e * 64 + lane];
#pragma unroll
  for (int m = 1; m < 64; m <<= 1) s += __shfl_xor(s, m, 64);
  if (lane == 0) aux[row] = s + lb[0] + cb[0];
}

// ---------------------------------------------------------------------------
// CIN mega-kernel. Block = 4 b-values -> 128 rows r=(b_local*32+d), 128 channels.
// Layer0: C0 = Y0 @ W0^T, Y0[r][k=(m*40+n)] = X[b][m][d]*X[b][n][d], K=1600.
//   relu+bias; ch 0..63 -> h1 (LDS bf16); ch 64..127 -> aux partial (.*cw[o-64]).
// Layer1: C1 = Y1 @ W1^T, Y1[r][k=(m*64+n)] = X[b][m][d]*h1[n][r], K=2560.
//   relu+bias; aux partial (.*cw[64+o]); then aux[b] += sum_d.
// MFMA 16x16x32 bf16; A generated in LDS (u32 bf16-pairs), B staged from
// pre-swizzled weights.
// ---------------------------------------------------------------------------
__device__ __forceinline__ void mfma_step(const u32* Apair, const u32* Btile,
                                          f32x4 acc[4][4], int wr, int wc, int q, int rl,
                                          int lane) {
  short8 af[4];
#pragma unroll
  for (int u = 0; u < 4; ++u) {
    int rt = 4 * wr + u;
    uint4 av;
    av.x = Apair[((0 * 8 + rt) * 4 + q) * 16 + rl];
    av.y = Apair[((1 * 8 + rt) * 4 + q) * 16 + rl];
    av.z = Apair[((2 * 8 + rt) * 4 + q) * 16 + rl];
    av.w = Apair[((3 * 8 + rt) * 4 + q) * 16 + rl];
    af[u] = __builtin_bit_cast(short8, av);
  }
#pragma unroll
  for (int tt = 0; tt < 4; ++tt) {
    int tg = 4 * wc + tt;
    uint4 bv = *(const uint4*)&Btile[(tg * 64 + lane) * 4];
    short8 bfv = __builtin_bit_cast(short8, bv);
#pragma unroll
    for (int u = 0; u < 4; ++u)
      acc[u][tt] = __builtin_amdgcn_mfma_f32_16x16x32_bf16(af[u], bfv, acc[u][tt], 0, 0, 0);
  }
}

__global__ __launch_bounds__(256, 2) void cin_kernel(
    const float* __restrict__ emb, const unsigned short* __restrict__ wz0,
    const unsigned short* __restrict__ wz1, const float* __restrict__ b0v,
    const float* __restrict__ b1v, const float* __restrict__ cw,
    float* __restrict__ aux) {
  __shared__ float Xl[4 * 40 * 36];          // 22.5 KB, rows padded to 36
  __shared__ u32 Apair[2048];                // 8 KB: [jp][rt][q][rl] bf16-pairs
  __shared__ u32 Btile[2048];                // 8 KB: frag-block order
  __shared__ unsigned short h1t[64 * 136];   // 17 KB: h1[n][r], bf16, pad 136
  __shared__ float auxacc[128];

  const int tid = threadIdx.x;
  const int lane = tid & 63;
  const int w = tid >> 6;
  const int wr = w >> 1, wc = w & 1;
  const int rl = lane & 15, q = lane >> 4;
  const int b0blk = blockIdx.x * 4;

  // stage emb tile -> Xl
#pragma unroll
  for (int i = 0; i < 5; ++i) {
    int e = i * 1024 + tid * 4;
    int b = e / 1280;
    int rem = e - b * 1280;
    int m = rem >> 5, d = rem & 31;
    float4 v = *(const float4*)(emb + (size_t)b0blk * 1280 + e);
    *(float4*)&Xl[(b * 40 + m) * 36 + d] = v;
  }
  if (tid < 128) auxacc[tid] = 0.f;

  // generator thread coords: 16 k-pairs x 4 b x (wave-> d-octet)
  const int kp = tid & 15;
  const int jp = kp & 3, qg = kp >> 2;
  const int bg = (tid >> 4) & 3;
  const int dq4 = tid >> 6;  // d-base = dq4*8
  const float* xb = &Xl[bg * 40 * 36];

  f32x4 acc[4][4];
#pragma unroll
  for (int u = 0; u < 4; ++u)
#pragma unroll
    for (int t = 0; t < 4; ++t) acc[u][t] = f32x4{0.f, 0.f, 0.f, 0.f};

  // =============== layer 0, K = 1600 ===============
  for (int kc = 0; kc < 50; ++kc) {
    const int kk = kc * 32;
    __syncthreads();
    {
      int k0 = kk + 2 * kp;
      int m0 = k0 / 40, n0 = k0 - m0 * 40;
      int k1 = k0 + 1;
      int m1 = k1 / 40, n1 = k1 - m1 * 40;
#pragma unroll
      for (int dd = 0; dd < 2; ++dd) {
        int d0 = dq4 * 8 + dd * 4;
        int rt = 2 * bg + (d0 >> 4);
        int rla = d0 & 15;
        float4 xm0 = *(const float4*)&xb[m0 * 36 + d0];
        float4 xn0 = *(const float4*)&xb[n0 * 36 + d0];
        float4 xm1 = *(const float4*)&xb[m1 * 36 + d0];
        float4 xn1 = *(const float4*)&xb[n1 * 36 + d0];
        uint4 o;
        o.x = pk_bf16(xm0.x * xn0.x, xm1.x * xn1.x);
        o.y = pk_bf16(xm0.y * xn0.y, xm1.y * xn1.y);
        o.z = pk_bf16(xm0.z * xn0.z, xm1.z * xn1.z);
        o.w = pk_bf16(xm0.w * xn0.w, xm1.w * xn1.w);
        *(uint4*)&Apair[((jp * 8 + rt) * 4 + qg) * 16 + rla] = o;
      }
      const u32* gb = (const u32*)wz0 + (size_t)kc * 2048 + tid * 8;
      uint4 v0 = *(const uint4*)gb;
      uint4 v1 = *(const uint4*)(gb + 4);
      *(uint4*)&Btile[tid * 8] = v0;
      *(uint4*)&Btile[tid * 8 + 4] = v1;
    }
    __syncthreads();
    mfma_step(Apair, Btile, acc, wr, wc, q, rl, lane);
  }

  // epilogue layer0: bias+relu; split
  if (wc == 0) {
#pragma unroll
    for (int u = 0; u < 4; ++u) {
      int r0 = 64 * wr + 16 * u + 4 * q;
#pragma unroll
      for (int tt = 0; tt < 4; ++tt) {
        int o = 16 * tt + rl;
        float bb = b0v[o];
        float v0 = fmaxf(acc[u][tt][0] + bb, 0.f);
        float v1 = fmaxf(acc[u][tt][1] + bb, 0.f);
        float v2 = fmaxf(acc[u][tt][2] + bb, 0.f);
        float v3 = fmaxf(acc[u][tt][3] + bb, 0.f);
        uint2 pw;
        pw.x = pk_bf16(v0, v1);
        pw.y = pk_bf16(v2, v3);
        *(uint2*)&h1t[o * 136 + r0] = pw;
      }
    }
  } else {
#pragma unroll
    for (int u = 0; u < 4; ++u)
#pragma unroll
      for (int i = 0; i < 4; ++i) {
        float s = 0.f;
#pragma unroll
        for (int tt = 0; tt < 4; ++tt) {
          int o = 64 + 16 * tt + rl;
          s += fmaxf(acc[u][tt][i] + b0v[o], 0.f) * cw[o - 64];
        }
        s += __shfl_xor(s, 1, 16);
        s += __shfl_xor(s, 2, 16);
        s += __shfl_xor(s, 4, 16);
        s += __shfl_xor(s, 8, 16);
        if (rl == 0) atomicAdd(&auxacc[64 * wr + 16 * u + 4 * q + i], s);
      }
  }
#pragma unroll
  for (int u = 0; u < 4; ++u)
#pragma unroll
    for (int t = 0; t < 4; ++t) acc[u][t] = f32x4{0.f, 0.f, 0.f, 0.f};

  // =============== layer 1, K = 2560 (chunk kc: m = kk>>6, n = kk&32 ..) ====
  for (int kc = 0; kc < 80; ++kc) {
    const int kk = kc * 32;
    const int mrow = kk >> 6;
    const int nbase = kk & 32;
    __syncthreads();
    {
      int n0 = nbase + 2 * kp, n1 = n0 + 1;
#pragma unroll
      for (int dd = 0; dd < 2; ++dd) {
        int d0 = dq4 * 8 + dd * 4;
        int rt = 2 * bg + (d0 >> 4);
        int rla = d0 & 15;
        int r0 = 32 * bg + d0;
        float4 xm = *(const float4*)&xb[mrow * 36 + d0];
        uint2 u0 = *(const uint2*)&h1t[n0 * 136 + r0];
        uint2 u1 = *(const uint2*)&h1t[n1 * 136 + r0];
        uint4 o;
        o.x = pk_bf16(xm.x * bflo(u0.x), xm.x * bflo(u1.x));
        o.y = pk_bf16(xm.y * bfhi(u0.x), xm.y * bfhi(u1.x));
        o.z = pk_bf16(xm.z * bflo(u0.y), xm.z * bflo(u1.y));
        o.w = pk_bf16(xm.w * bfhi(u0.y), xm.w * bfhi(u1.y));
        *(uint4*)&Apair[((jp * 8 + rt) * 4 + qg) * 16 + rla] = o;
      }
      const u32* gb = (const u32*)wz1 + (size_t)kc * 2048 + tid * 8;
      uint4 v0 = *(const uint4*)gb;
      uint4 v1 = *(const uint4*)(gb + 4);
      *(uint4*)&Btile[tid * 8] = v0;
      *(uint4*)&Btile[tid * 8 + 4] = v1;
    }
    __syncthreads();
    mfma_step(Apair, Btile, acc, wr, wc, q, rl, lane);
  }

  // epilogue layer1: bias+relu, weighted aux partial
#pragma unroll
  for (int u = 0; u < 4; ++u)
#pragma unroll
    for (int i = 0; i < 4; ++i) {
      float s = 0.f;
#pragma unroll
      for (int tt = 0; tt < 4; ++tt) {
        int o = 64 * wc + 16 * tt + rl;
        s += fmaxf(acc[u][tt][i] + b1v[o], 0.f) * cw[64 + o];
      }
      s += __shfl_xor(s, 1, 16);
      s += __shfl_xor(s, 2, 16);
      s += __shfl_xor(s, 4, 16);
      s += __shfl_xor(s, 8, 16);
      if (rl == 0) atomicAdd(&auxacc[64 * wr + 16 * u + 4 * q + i], s);
    }
  __syncthreads();
  if (tid < 4) {
    float s = 0.f;
    for (int d = 0; d < 32; ++d) s += auxacc[tid * 32 + d];
    aux[b0blk + tid] += s;  // lin_kernel ran first on the stream
  }
}

// ---------------------------------------------------------------------------
// Deep tower GEMM: C[M][N] = A[M][K] @ Wswz^T + bias. NT = N-tiles per block
// (8 -> BN=128, 4 -> BN=64). AF32: A is f32, cvt to bf16 during staging.
// ---------------------------------------------------------------------------
template <int NT, bool AF32>
__global__ __launch_bounds__(256, 2) void gemm_deep(
    const void* __restrict__ Ain, const unsigned short* __restrict__ Bswz,
    const float* __restrict__ bias, float* __restrict__ Cout, int M, int N, int K) {
  __shared__ unsigned short At[128 * 32];
  __shared__ u32 Bt[NT * 256];
  const int tid = threadIdx.x, lane = tid & 63, w = tid >> 6;
  const int wr = w >> 1, wc = w & 1, rl = lane & 15, q = lane >> 4;
  const int r0 = blockIdx.x * 128, c0 = blockIdx.y * (NT * 16);
  const int ntg = N >> 4;
  constexpr int WT = NT / 2;
  f32x4 acc[4][WT];
#pragma unroll
  for (int u = 0; u < 4; ++u)
#pragma unroll
    for (int t = 0; t < WT; ++t) acc[u][t] = f32x4{0.f, 0.f, 0.f, 0.f};

  for (int kk = 0; kk < K; kk += 32) {
    __syncthreads();
    {
      int r = tid >> 1, kh = (tid & 1) * 16;
      if constexpr (AF32) {
        const float* A = (const float*)Ain;
        const float* src = A + (size_t)(r0 + r) * K + kk + kh;
        float4 v0 = *(const float4*)src;
        float4 v1 = *(const float4*)(src + 4);
        float4 v2 = *(const float4*)(src + 8);
        float4 v3 = *(const float4*)(src + 12);
        uint4 p0, p1;
        p0.x = pk_bf16(v0.x, v0.y); p0.y = pk_bf16(v0.z, v0.w);
        p0.z = pk_bf16(v1.x, v1.y); p0.w = pk_bf16(v1.z, v1.w);
        p1.x = pk_bf16(v2.x, v2.y); p1.y = pk_bf16(v2.z, v2.w);
        p1.z = pk_bf16(v3.x, v3.y); p1.w = pk_bf16(v3.z, v3.w);
        uint4* dst = (uint4*)&At[r * 32 + kh];
        dst[0] = p0;
        dst[1] = p1;
      } else {
        const unsigned short* A = (const unsigned short*)Ain;
        const uint4* src = (const uint4*)(A + (size_t)(r0 + r) * K + kk + kh);
        uint4* dst = (uint4*)&At[r * 32 + kh];
        dst[0] = src[0];
        dst[1] = src[1];
      }
      const u32* gb = (const u32*)Bswz + ((size_t)(kk >> 5) * ntg + (c0 >> 4)) * 256;
#pragma unroll
      for (int i = 0; i < NT; ++i) Bt[tid + i * 256] = gb[tid + i * 256];
    }
    __syncthreads();
    short8 af[4];
#pragma unroll
    for (int u = 0; u < 4; ++u) {
      int rt = 4 * wr + u;
      uint4 av = *(const uint4*)&At[(16 * rt + rl) * 32 + q * 8];
      af[u] = __builtin_bit_cast(short8, av);
    }
#pragma unroll
    for (int tt = 0; tt < WT; ++tt) {
      int tg = WT * wc + tt;
      uint4 bv = *(const uint4*)&Bt[(tg * 64 + lane) * 4];
      short8 bfv = __builtin_bit_cast(short8, bv);
#pragma unroll
      for (int u = 0; u < 4; ++u)
        acc[u][tt] = __builtin_amdgcn_mfma_f32_16x16x32_bf16(af[u], bfv, acc[u][tt], 0, 0, 0);
    }
  }
#pragma unroll
  for (int u = 0; u < 4; ++u) {
    int rr = r0 + 64 * wr + 16 * u + 4 * q;
#pragma unroll
    for (int tt = 0; tt < WT; ++tt) {
      int o = c0 + (WT * wc + tt) * 16 + rl;
      float bb = bias[o];
#pragma unroll
      for (int i = 0; i < 4; ++i)
        Cout[(size_t)(rr + i) * N + o] = acc[u][tt][i] + bb;
    }
  }
}

// ---------------------------------------------------------------------------
// LayerNorm + relu (+ cast). One wave per row.
// ---------------------------------------------------------------------------
template <int D, bool OUTF32>
__global__ void ln_relu_kernel(const float* __restrict__ in, const float* __restrict__ g,
                               const float* __restrict__ bt, void* __restrict__ out) {
  int row = blockIdx.x * 4 + (threadIdx.x >> 6);
  int lane = threadIdx.x & 63;
  constexpr int E = D / 64;
  const float* src = in + (size_t)row * D;
  float v[E], s1 = 0.f, s2 = 0.f;
#pragma unroll
  for (int e = 0; e < E; ++e) {
    v[e] = src[e * 64 + lane];
    s1 += v[e];
    s2 += v[e] * v[e];
  }
#pragma unroll
  for (int m = 1; m < 64; m <<= 1) {
    s1 += __shfl_xor(s1, m, 64);
    s2 += __shfl_xor(s2, m, 64);
  }
  float mu = s1 / (float)D;
  float rs = rsqrtf(s2 / (float)D - mu * mu + 1e-5f);
#pragma unroll
  for (int e = 0; e < E; ++e) {
    int c = e * 64 + lane;
    float y = fmaxf((v[e] - mu) * rs * g[c] + bt[c], 0.f);
    if constexpr (OUTF32)
      ((float*)out)[(size_t)row * D + c] = y;
    else
      ((unsigned short*)out)[(size_t)row * D + c] = (unsigned short)bf16_rne(y);
  }
}

// ---------------------------------------------------------------------------
extern "C" void kernel_launch(void* const* d_in, const int* in_sizes, int n_in,
                              void* d_out, int out_size, void* d_ws, size_t ws_size,
                              hipStream_t stream) {
  const float* x = (const float*)d_in[0];
  const float* emb = (const float*)d_in[1];
  const float* lin_w = (const float*)d_in[2];
  const float* lin_b = (const float*)d_in[3];
  const float* cw0 = (const float*)d_in[4];
  const float* cb0 = (const float*)d_in[5];
  const float* cw1 = (const float*)d_in[6];
  const float* cb1 = (const float*)d_in[7];
  const float* cow = (const float*)d_in[8];
  const float* cob = (const float*)d_in[9];
  const float* dw0 = (const float*)d_in[10];
  const float* db0 = (const float*)d_in[11];
  const float* g0 = (const float*)d_in[12];
  const float* be0 = (const float*)d_in[13];
  const float* dw1 = (const float*)d_in[14];
  const float* db1 = (const float*)d_in[15];
  const float* g1 = (const float*)d_in[16];
  const float* be1 = (const float*)d_in[17];
  const float* dw2 = (const float*)d_in[18];
  const float* db2 = (const float*)d_in[19];
  const float* g2 = (const float*)d_in[20];
  const float* be2 = (const float*)d_in[21];

  char* ws = (char*)d_ws;
  unsigned short* wz0 = (unsigned short*)(ws + 0);         // 409600
  unsigned short* wz1 = (unsigned short*)(ws + 409600);    // 655360
  unsigned short* wzd0 = (unsigned short*)(ws + 1064960);  // 655360
  unsigned short* wzd1 = (unsigned short*)(ws + 1720320);  // 65536
  unsigned short* wzd2 = (unsigned short*)(ws + 1785856);  // 16384
  float* t0 = (float*)(ws + 1802240);                      // 16777216
  unsigned short* h0b = (unsigned short*)(ws + 18579456);  // 8388608
  float* t1 = (float*)(ws + 26968064);                     // 8388608
  unsigned short* h1b = (unsigned short*)(ws + 35356672);  // 4194304
  float* t2 = (float*)(ws + 39550976);                     // 4194304  (tot 43.7MB)

  float* h_out = (float*)d_out;
  float* aux = h_out + (size_t)16384 * 64;

  // weight prep
  swz_kernel<<<(1600 * 128 + 255) / 256, 256, 0, stream>>>(cw0, wz0, 128, 1600);
  swz_kernel<<<(2560 * 128 + 255) / 256, 256, 0, stream>>>(cw1, wz1, 128, 2560);
  swz_kernel<<<(1280 * 256 + 255) / 256, 256, 0, stream>>>(dw0, wzd0, 256, 1280);
  swz_kernel<<<(256 * 128 + 255) / 256, 256, 0, stream>>>(dw1, wzd1, 128, 256);
  swz_kernel<<<(128 * 64 + 255) / 256, 256, 0, stream>>>(dw2, wzd2, 64, 128);

  // aux = linear part first, then CIN adds its contribution
  lin_kernel<<<4096, 256, 0, stream>>>(x, lin_w, lin_b, cob, aux);
  cin_kernel<<<4096, 256, 0, stream>>>(emb, wz0, wz1, cb0, cb1, cow, aux);

  // deep tower
  gemm_deep<8, true><<<dim3(128, 2), 256, 0, stream>>>(x, wzd0, db0, t0, 16384, 256, 1280);
  ln_relu_kernel<256, false><<<4096, 256, 0, stream>>>(t0, g0, be0, h0b);
  gemm_deep<8, false><<<dim3(128, 1), 256, 0, stream>>>(h0b, wzd1, db1, t1, 16384, 128, 256);
  ln_relu_kernel<128, false><<<4096, 256, 0, stream>>>(t1, g1, be1, h1b);
  gemm_deep<4, false><<<dim3(128, 1), 256, 0, stream>>>(h1b, wzd2, db2, t2, 16384, 64, 128);
  ln_relu_kernel<64, true><<<4096, 256, 0, stream>>>(t2, g2, be2, h_out);
}

// Round 3
// 982.707 us; speedup vs baseline: 1.2514x; 1.2514x over previous
//
#include <hip/hip_runtime.h>
#include <hip/hip_bf16.h>

typedef unsigned int u32;
typedef __attribute__((ext_vector_type(8))) short short8;
typedef __attribute__((ext_vector_type(4))) float f32x4;

__device__ __forceinline__ u32 bf16_rne(float f) {
  u32 u = __builtin_bit_cast(u32, f);
  return (u + 0x7fffu + ((u >> 16) & 1u)) >> 16;
}
// packed pair (a low 16, b high 16) via hw v_cvt_pk_bf16_f32
__device__ __forceinline__ u32 pk_bf16(float a, float b) {
  union { __hip_bfloat162 h; u32 u; } cv;
  cv.h = __float22bfloat162_rn(make_float2(a, b));
  return cv.u;
}
__device__ __forceinline__ float bflo(u32 u) { return __builtin_bit_cast(float, u << 16); }
__device__ __forceinline__ float bfhi(u32 u) { return __builtin_bit_cast(float, u & 0xffff0000u); }

__device__ __forceinline__ void unpack8(uint4 v, float* f) {
  f[0] = bflo(v.x); f[1] = bfhi(v.x);
  f[2] = bflo(v.y); f[3] = bfhi(v.y);
  f[4] = bflo(v.z); f[5] = bfhi(v.z);
  f[6] = bflo(v.w); f[7] = bfhi(v.w);
}

// async global->LDS, 16B per lane, wave-uniform LDS base
__device__ __forceinline__ void glds16(const u32* g, u32* l) {
  __builtin_amdgcn_global_load_lds((const __attribute__((address_space(1))) u32*)g,
                                   (__attribute__((address_space(3))) u32*)l, 16, 0, 0);
}

// ---------------------------------------------------------------------------
// Weight swizzle: W [N][K] f32 -> bf16 frag-block order (1KB per 16x32 frag).
// ---------------------------------------------------------------------------
__global__ void swz_kernel(const float* __restrict__ W, unsigned short* __restrict__ out,
                           int N, int K) {
  int tid = blockIdx.x * 256 + threadIdx.x;
  if (tid >= N * K) return;
  int j = tid & 7, l = (tid >> 3) & 63, rest = tid >> 9;
  int nt = N >> 4;
  int t = rest % nt, k32 = rest / nt;
  int o = t * 16 + (l & 15);
  int k = k32 * 32 + (l >> 4) * 8 + j;
  out[tid] = (unsigned short)bf16_rne(W[(size_t)o * K + k]);
}

// ---------------------------------------------------------------------------
__global__ void lin_kernel(const float* __restrict__ x, const float* __restrict__ lw,
                           const float* __restrict__ lb, const float* __restrict__ cb,
                           float* __restrict__ aux) {
  int row = blockIdx.x * 4 + (threadIdx.x >> 6);
  int lane = threadIdx.x & 63;
  const float* xr = x + (size_t)row * 1280;
  float s = 0.f;
#pragma unroll
  for (int e = 0; e < 20; ++e) s += xr[e * 64 + lane] * lw[e * 64 + lane];
#pragma unroll
  for (int m = 1; m < 64; m <<= 1) s += __shfl_xor(s, m, 64);
  if (lane == 0) aux[row] = s + lb[0] + cb[0];
}

// ---------------------------------------------------------------------------
// CIN mega-kernel (see R2 notes). LDS 47.1KB -> 3 blocks/CU.
//  Xw: bf16-pair packed X, row stride 20 words, octet-XOR swizzle by (m>>3)&3.
//  Apair: [jb][rt][qg][rla] u32 pairs; generator writes contiguous 8*tid.
//  h1w:  [n][r-pairs] u32, row stride 68 words, r-octet XOR swizzle by (n>>3)&3.
// ---------------------------------------------------------------------------
__device__ __forceinline__ int xaddr(int b, int m, int o) {
  return (b * 40 + m) * 20 + (((o ^ (m >> 3)) & 3) << 2);
}

__device__ __forceinline__ void mfma_step(const u32* Apair, const u32* Btile,
                                          f32x4 acc[4][4], int wr, int wc, int q, int rl,
                                          int lane) {
  short8 af[4];
#pragma unroll
  for (int u = 0; u < 4; ++u) {
    int rt = 4 * wr + u;
    uint4 av;
    av.x = Apair[((0 * 8 + rt) * 4 + q) * 16 + rl];
    av.y = Apair[((1 * 8 + rt) * 4 + q) * 16 + rl];
    av.z = Apair[((2 * 8 + rt) * 4 + q) * 16 + rl];
    av.w = Apair[((3 * 8 + rt) * 4 + q) * 16 + rl];
    af[u] = __builtin_bit_cast(short8, av);
  }
#pragma unroll
  for (int tt = 0; tt < 4; ++tt) {
    int tg = 4 * wc + tt;
    uint4 bv = *(const uint4*)&Btile[(tg * 64 + lane) * 4];
    short8 bfv = __builtin_bit_cast(short8, bv);
#pragma unroll
    for (int u = 0; u < 4; ++u)
      acc[u][tt] = __builtin_amdgcn_mfma_f32_16x16x32_bf16(af[u], bfv, acc[u][tt], 0, 0, 0);
  }
}

__global__ __launch_bounds__(256, 3) void cin_kernel(
    const float* __restrict__ emb, const unsigned short* __restrict__ wz0,
    const unsigned short* __restrict__ wz1, const float* __restrict__ b0v,
    const float* __restrict__ b1v, const float* __restrict__ cw,
    float* __restrict__ aux) {
  __shared__ u32 Xw[4 * 40 * 20];   // 12.8 KB packed-bf16 X
  __shared__ u32 Apair[2048];       // 8 KB
  __shared__ u32 Btile[2048];       // 8 KB
  __shared__ u32 h1w[64 * 68];      // 17 KB
  __shared__ float auxacc[128];

  const int tid = threadIdx.x;
  const int lane = tid & 63;
  const int w = tid >> 6;
  const int wr = w >> 1, wc = w & 1;
  const int rl = lane & 15, q = lane >> 4;
  const int b0blk = blockIdx.x * 4;

  // stage emb -> Xw (bf16 pairs, swizzled octets)
#pragma unroll
  for (int i = 0; i < 3; ++i) {
    int idx = i * 256 + tid;  // uint4-granule over 640
    if (idx < 640) {
      int b = idx / 160;
      int rf = (idx - b * 160) * 8;
      int m = rf >> 5, o = (rf & 31) >> 3;
      const float* src = emb + (size_t)b0blk * 1280 + idx * 8;
      float4 v0 = *(const float4*)src;
      float4 v1 = *(const float4*)(src + 4);
      uint4 pw;
      pw.x = pk_bf16(v0.x, v0.y); pw.y = pk_bf16(v0.z, v0.w);
      pw.z = pk_bf16(v1.x, v1.y); pw.w = pk_bf16(v1.z, v1.w);
      *(uint4*)&Xw[xaddr(b, m, o)] = pw;
    }
  }
  if (tid < 128) auxacc[tid] = 0.f;

  // generator coords: thread owns Apair words [8*tid, 8*tid+8)
  const int jb = tid >> 6;            // == wave id
  const int grt = (tid >> 3) & 7;
  const int gqg = (tid >> 1) & 3;
  const int s = tid & 1;              // rla0 = 8*s
  const int gb_ = grt >> 1;           // b_local
  const int go = 2 * (grt & 1) + s;   // d-octet index

  f32x4 acc[4][4];
#pragma unroll
  for (int u = 0; u < 4; ++u)
#pragma unroll
    for (int t = 0; t < 4; ++t) acc[u][t] = f32x4{0.f, 0.f, 0.f, 0.f};

  // =============== layer 0, K = 1600 ===============
  {
    int k0i = gqg * 8 + jb * 2;
    int m0 = 0, n0 = k0i, m1 = 0, n1 = k0i + 1;
    for (int kc = 0; kc < 50; ++kc) {
      __syncthreads();
      {
        uint4 vm0 = *(const uint4*)&Xw[xaddr(gb_, m0, go)];
        uint4 vn0 = *(const uint4*)&Xw[xaddr(gb_, n0, go)];
        uint4 vm1 = *(const uint4*)&Xw[xaddr(gb_, m1, go)];
        uint4 vn1 = *(const uint4*)&Xw[xaddr(gb_, n1, go)];
        float fm0[8], fn0[8], fm1[8], fn1[8];
        unpack8(vm0, fm0); unpack8(vn0, fn0);
        unpack8(vm1, fm1); unpack8(vn1, fn1);
        uint4 o0, o1;
        o0.x = pk_bf16(fm0[0] * fn0[0], fm1[0] * fn1[0]);
        o0.y = pk_bf16(fm0[1] * fn0[1], fm1[1] * fn1[1]);
        o0.z = pk_bf16(fm0[2] * fn0[2], fm1[2] * fn1[2]);
        o0.w = pk_bf16(fm0[3] * fn0[3], fm1[3] * fn1[3]);
        o1.x = pk_bf16(fm0[4] * fn0[4], fm1[4] * fn1[4]);
        o1.y = pk_bf16(fm0[5] * fn0[5], fm1[5] * fn1[5]);
        o1.z = pk_bf16(fm0[6] * fn0[6], fm1[6] * fn1[6]);
        o1.w = pk_bf16(fm0[7] * fn0[7], fm1[7] * fn1[7]);
        *(uint4*)&Apair[tid * 8] = o0;
        *(uint4*)&Apair[tid * 8 + 4] = o1;
        const u32* g = (const u32*)wz0 + (size_t)kc * 2048 + jb * 512 + lane * 4;
        glds16(g, &Btile[jb * 512]);
        glds16(g + 256, &Btile[jb * 512 + 256]);
      }
      // advance k by 32 (single wrap possible)
      n0 += 32; if (n0 >= 40) { n0 -= 40; ++m0; }
      n1 += 32; if (n1 >= 40) { n1 -= 40; ++m1; }
      __syncthreads();
      mfma_step(Apair, Btile, acc, wr, wc, q, rl, lane);
    }
  }

  // epilogue layer0: bias+relu; ch<64 -> h1w, ch>=64 -> aux partial
  if (wc == 0) {
#pragma unroll
    for (int u = 0; u < 4; ++u) {
      int r0q = 64 * wr + 16 * u + 4 * q;
      int ro = r0q >> 3, rq = (r0q & 7) >> 1;
#pragma unroll
      for (int tt = 0; tt < 4; ++tt) {
        int o = 16 * tt + rl;
        float bb = b0v[o];
        float v0 = fmaxf(acc[u][tt][0] + bb, 0.f);
        float v1 = fmaxf(acc[u][tt][1] + bb, 0.f);
        float v2 = fmaxf(acc[u][tt][2] + bb, 0.f);
        float v3 = fmaxf(acc[u][tt][3] + bb, 0.f);
        uint2 pw;
        pw.x = pk_bf16(v0, v1);
        pw.y = pk_bf16(v2, v3);
        *(uint2*)&h1w[o * 68 + ((ro ^ ((o >> 3) & 3)) << 2) + rq] = pw;
      }
    }
  } else {
#pragma unroll
    for (int u = 0; u < 4; ++u)
#pragma unroll
      for (int i = 0; i < 4; ++i) {
        float sle = 0.f;
#pragma unroll
        for (int tt = 0; tt < 4; ++tt) {
          int o = 64 + 16 * tt + rl;
          sle += fmaxf(acc[u][tt][i] + b0v[o], 0.f) * cw[o - 64];
        }
        sle += __shfl_xor(sle, 1, 16);
        sle += __shfl_xor(sle, 2, 16);
        sle += __shfl_xor(sle, 4, 16);
        sle += __shfl_xor(sle, 8, 16);
        if (rl == 0) atomicAdd(&auxacc[64 * wr + 16 * u + 4 * q + i], sle);
      }
  }
#pragma unroll
  for (int u = 0; u < 4; ++u)
#pragma unroll
    for (int t = 0; t < 4; ++t) acc[u][t] = f32x4{0.f, 0.f, 0.f, 0.f};

  // =============== layer 1, K = 2560 ===============
  {
    const int gro = 2 * grt + s;  // r-octet for this thread's rows
    for (int kc = 0; kc < 80; ++kc) {
      const int mrow = kc >> 1;
      const int n0 = ((kc & 1) << 5) + gqg * 8 + jb * 2;
      const int n1 = n0 + 1;
      __syncthreads();
      {
        uint4 vm = *(const uint4*)&Xw[xaddr(gb_, mrow, go)];
        uint4 vh0 = *(const uint4*)&h1w[n0 * 68 + ((gro ^ ((n0 >> 3) & 3)) << 2)];
        uint4 vh1 = *(const uint4*)&h1w[n1 * 68 + ((gro ^ ((n1 >> 3) & 3)) << 2)];
        float fm[8], g0[8], g1[8];
        unpack8(vm, fm); unpack8(vh0, g0); unpack8(vh1, g1);
        uint4 o0, o1;
        o0.x = pk_bf16(fm[0] * g0[0], fm[0] * g1[0]);
        o0.y = pk_bf16(fm[1] * g0[1], fm[1] * g1[1]);
        o0.z = pk_bf16(fm[2] * g0[2], fm[2] * g1[2]);
        o0.w = pk_bf16(fm[3] * g0[3], fm[3] * g1[3]);
        o1.x = pk_bf16(fm[4] * g0[4], fm[4] * g1[4]);
        o1.y = pk_bf16(fm[5] * g0[5], fm[5] * g1[5]);
        o1.z = pk_bf16(fm[6] * g0[6], fm[6] * g1[6]);
        o1.w = pk_bf16(fm[7] * g0[7], fm[7] * g1[7]);
        *(uint4*)&Apair[tid * 8] = o0;
        *(uint4*)&Apair[tid * 8 + 4] = o1;
        const u32* g = (const u32*)wz1 + (size_t)kc * 2048 + jb * 512 + lane * 4;
        glds16(g, &Btile[jb * 512]);
        glds16(g + 256, &Btile[jb * 512 + 256]);
      }
      __syncthreads();
      mfma_step(Apair, Btile, acc, wr, wc, q, rl, lane);
    }
  }

  // epilogue layer1
#pragma unroll
  for (int u = 0; u < 4; ++u)
#pragma unroll
    for (int i = 0; i < 4; ++i) {
      float sle = 0.f;
#pragma unroll
      for (int tt = 0; tt < 4; ++tt) {
        int o = 64 * wc + 16 * tt + rl;
        sle += fmaxf(acc[u][tt][i] + b1v[o], 0.f) * cw[64 + o];
      }
      sle += __shfl_xor(sle, 1, 16);
      sle += __shfl_xor(sle, 2, 16);
      sle += __shfl_xor(sle, 4, 16);
      sle += __shfl_xor(sle, 8, 16);
      if (rl == 0) atomicAdd(&auxacc[64 * wr + 16 * u + 4 * q + i], sle);
    }
  __syncthreads();
  if (tid < 4) {
    float ssum = 0.f;
    for (int d = 0; d < 32; ++d) ssum += auxacc[tid * 32 + d];
    aux[b0blk + tid] += ssum;  // lin_kernel ran first
  }
}

// ---------------------------------------------------------------------------
// Deep tower GEMM. At padded to 40 shorts/row; B via global_load_lds.
// ---------------------------------------------------------------------------
template <int NT, bool AF32>
__global__ __launch_bounds__(256, 2) void gemm_deep(
    const void* __restrict__ Ain, const unsigned short* __restrict__ Bswz,
    const float* __restrict__ bias, float* __restrict__ Cout, int M, int N, int K) {
  __shared__ unsigned short At[128 * 40];
  __shared__ u32 Bt[NT * 256];
  const int tid = threadIdx.x, lane = tid & 63, w = tid >> 6;
  const int wr = w >> 1, wc = w & 1, rl = lane & 15, q = lane >> 4;
  const int r0 = blockIdx.x * 128, c0 = blockIdx.y * (NT * 16);
  const int ntg = N >> 4;
  constexpr int WT = NT / 2;
  f32x4 acc[4][WT];
#pragma unroll
  for (int u = 0; u < 4; ++u)
#pragma unroll
    for (int t = 0; t < WT; ++t) acc[u][t] = f32x4{0.f, 0.f, 0.f, 0.f};

  for (int kk = 0; kk < K; kk += 32) {
    __syncthreads();
    {
      int r = tid >> 1, kh = (tid & 1) * 16;
      if constexpr (AF32) {
        const float* A = (const float*)Ain;
        const float* src = A + (size_t)(r0 + r) * K + kk + kh;
        float4 v0 = *(const float4*)src;
        float4 v1 = *(const float4*)(src + 4);
        float4 v2 = *(const float4*)(src + 8);
        float4 v3 = *(const float4*)(src + 12);
        uint4 p0, p1;
        p0.x = pk_bf16(v0.x, v0.y); p0.y = pk_bf16(v0.z, v0.w);
        p0.z = pk_bf16(v1.x, v1.y); p0.w = pk_bf16(v1.z, v1.w);
        p1.x = pk_bf16(v2.x, v2.y); p1.y = pk_bf16(v2.z, v2.w);
        p1.z = pk_bf16(v3.x, v3.y); p1.w = pk_bf16(v3.z, v3.w);
        uint4* dst = (uint4*)&At[r * 40 + kh];
        dst[0] = p0;
        dst[1] = p1;
      } else {
        const unsigned short* A = (const unsigned short*)Ain;
        const uint4* src = (const uint4*)(A + (size_t)(r0 + r) * K + kk + kh);
        uint4* dst = (uint4*)&At[r * 40 + kh];
        dst[0] = src[0];
        dst[1] = src[1];
      }
      const u32* gb = (const u32*)Bswz + ((size_t)(kk >> 5) * ntg + (c0 >> 4)) * 256;
      constexpr int WW = NT * 64;  // words per wave
#pragma unroll
      for (int j = 0; j < NT / 4; ++j)
        glds16(gb + w * WW + j * 256 + lane * 4, &Bt[w * WW + j * 256]);
    }
    __syncthreads();
    short8 af[4];
#pragma unroll
    for (int u = 0; u < 4; ++u) {
      int rt = 4 * wr + u;
      uint4 av = *(const uint4*)&At[(16 * rt + rl) * 40 + q * 8];
      af[u] = __builtin_bit_cast(short8, av);
    }
#pragma unroll
    for (int tt = 0; tt < WT; ++tt) {
      int tg = WT * wc + tt;
      uint4 bv = *(const uint4*)&Bt[(tg * 64 + lane) * 4];
      short8 bfv = __builtin_bit_cast(short8, bv);
#pragma unroll
      for (int u = 0; u < 4; ++u)
        acc[u][tt] = __builtin_amdgcn_mfma_f32_16x16x32_bf16(af[u], bfv, acc[u][tt], 0, 0, 0);
    }
  }
#pragma unroll
  for (int u = 0; u < 4; ++u) {
    int rr = r0 + 64 * wr + 16 * u + 4 * q;
#pragma unroll
    for (int tt = 0; tt < WT; ++tt) {
      int o = c0 + (WT * wc + tt) * 16 + rl;
      float bb = bias[o];
#pragma unroll
      for (int i = 0; i < 4; ++i)
        Cout[(size_t)(rr + i) * N + o] = acc[u][tt][i] + bb;
    }
  }
}

// ---------------------------------------------------------------------------
template <int D, bool OUTF32>
__global__ void ln_relu_kernel(const float* __restrict__ in, const float* __restrict__ g,
                               const float* __restrict__ bt, void* __restrict__ out) {
  int row = blockIdx.x * 4 + (threadIdx.x >> 6);
  int lane = threadIdx.x & 63;
  constexpr int E = D / 64;
  const float* src = in + (size_t)row * D;
  float v[E], s1 = 0.f, s2 = 0.f;
#pragma unroll
  for (int e = 0; e < E; ++e) {
    v[e] = src[e * 64 + lane];
    s1 += v[e];
    s2 += v[e] * v[e];
  }
#pragma unroll
  for (int m = 1; m < 64; m <<= 1) {
    s1 += __shfl_xor(s1, m, 64);
    s2 += __shfl_xor(s2, m, 64);
  }
  float mu = s1 / (float)D;
  float rs = rsqrtf(s2 / (float)D - mu * mu + 1e-5f);
#pragma unroll
  for (int e = 0; e < E; ++e) {
    int c = e * 64 + lane;
    float y = fmaxf((v[e] - mu) * rs * g[c] + bt[c], 0.f);
    if constexpr (OUTF32)
      ((float*)out)[(size_t)row * D + c] = y;
    else
      ((unsigned short*)out)[(size_t)row * D + c] = (unsigned short)bf16_rne(y);
  }
}

// ---------------------------------------------------------------------------
extern "C" void kernel_launch(void* const* d_in, const int* in_sizes, int n_in,
                              void* d_out, int out_size, void* d_ws, size_t ws_size,
                              hipStream_t stream) {
  const float* x = (const float*)d_in[0];
  const float* emb = (const float*)d_in[1];
  const float* lin_w = (const float*)d_in[2];
  const float* lin_b = (const float*)d_in[3];
  const float* cw0 = (const float*)d_in[4];
  const float* cb0 = (const float*)d_in[5];
  const float* cw1 = (const float*)d_in[6];
  const float* cb1 = (const float*)d_in[7];
  const float* cow = (const float*)d_in[8];
  const float* cob = (const float*)d_in[9];
  const float* dw0 = (const float*)d_in[10];
  const float* db0 = (const float*)d_in[11];
  const float* g0 = (const float*)d_in[12];
  const float* be0 = (const float*)d_in[13];
  const float* dw1 = (const float*)d_in[14];
  const float* db1 = (const float*)d_in[15];
  const float* g1 = (const float*)d_in[16];
  const float* be1 = (const float*)d_in[17];
  const float* dw2 = (const float*)d_in[18];
  const float* db2 = (const float*)d_in[19];
  const float* g2 = (const float*)d_in[20];
  const float* be2 = (const float*)d_in[21];

  char* ws = (char*)d_ws;
  unsigned short* wz0 = (unsigned short*)(ws + 0);         // 409600
  unsigned short* wz1 = (unsigned short*)(ws + 409600);    // 655360
  unsigned short* wzd0 = (unsigned short*)(ws + 1064960);  // 655360
  unsigned short* wzd1 = (unsigned short*)(ws + 1720320);  // 65536
  unsigned short* wzd2 = (unsigned short*)(ws + 1785856);  // 16384
  float* t0 = (float*)(ws + 1802240);                      // 16777216
  unsigned short* h0b = (unsigned short*)(ws + 18579456);  // 8388608
  float* t1 = (float*)(ws + 26968064);                     // 8388608
  unsigned short* h1b = (unsigned short*)(ws + 35356672);  // 4194304
  float* t2 = (float*)(ws + 39550976);                     // 4194304

  float* h_out = (float*)d_out;
  float* aux = h_out + (size_t)16384 * 64;

  swz_kernel<<<(1600 * 128 + 255) / 256, 256, 0, stream>>>(cw0, wz0, 128, 1600);
  swz_kernel<<<(2560 * 128 + 255) / 256, 256, 0, stream>>>(cw1, wz1, 128, 2560);
  swz_kernel<<<(1280 * 256 + 255) / 256, 256, 0, stream>>>(dw0, wzd0, 256, 1280);
  swz_kernel<<<(256 * 128 + 255) / 256, 256, 0, stream>>>(dw1, wzd1, 128, 256);
  swz_kernel<<<(128 * 64 + 255) / 256, 256, 0, stream>>>(dw2, wzd2, 64, 128);

  lin_kernel<<<4096, 256, 0, stream>>>(x, lin_w, lin_b, cob, aux);
  cin_kernel<<<4096, 256, 0, stream>>>(emb, wz0, wz1, cb0, cb1, cow, aux);

  gemm_deep<8, true><<<dim3(128, 2), 256, 0, stream>>>(x, wzd0, db0, t0, 16384, 256, 1280);
  ln_relu_kernel<256, false><<<4096, 256, 0, stream>>>(t0, g0, be0, h0b);
  gemm_deep<8, false><<<dim3(128, 1), 256, 0, stream>>>(h0b, wzd1, db1, t1, 16384, 128, 256);
  ln_relu_kernel<128, false><<<4096, 256, 0, stream>>>(t1, g1, be1, h1b);
  gemm_deep<4, false><<<dim3(128, 1), 256, 0, stream>>>(h1b, wzd2, db2, t2, 16384, 64, 128);
  ln_relu_kernel<64, true><<<4096, 256, 0, stream>>>(t2, g2, be2, h_out);
}

// Round 5
// 777.366 us; speedup vs baseline: 1.5820x; 1.2641x over previous
//
#include <hip/hip_runtime.h>
#include <hip/hip_bf16.h>

typedef unsigned int u32;
typedef __attribute__((ext_vector_type(8))) short short8;
typedef __attribute__((ext_vector_type(4))) float f32x4;

__device__ __forceinline__ u32 bf16_rne(float f) {
  u32 u = __builtin_bit_cast(u32, f);
  return (u + 0x7fffu + ((u >> 16) & 1u)) >> 16;
}
// packed pair (a low 16, b high 16) via hw v_cvt_pk_bf16_f32
__device__ __forceinline__ u32 pk_bf16(float a, float b) {
  union { __hip_bfloat162 h; u32 u; } cv;
  cv.h = __float22bfloat162_rn(make_float2(a, b));
  return cv.u;
}
__device__ __forceinline__ float bflo(u32 u) { return __builtin_bit_cast(float, u << 16); }
__device__ __forceinline__ float bfhi(u32 u) { return __builtin_bit_cast(float, u & 0xffff0000u); }

__device__ __forceinline__ void unpack8(uint4 v, float* f) {
  f[0] = bflo(v.x); f[1] = bfhi(v.x);
  f[2] = bflo(v.y); f[3] = bfhi(v.y);
  f[4] = bflo(v.z); f[5] = bfhi(v.z);
  f[6] = bflo(v.w); f[7] = bfhi(v.w);
}

__device__ __forceinline__ void glds16(const u32* g, u32* l) {
  __builtin_amdgcn_global_load_lds((const __attribute__((address_space(1))) u32*)g,
                                   (__attribute__((address_space(3))) u32*)l, 16, 0, 0);
}

// ---------------------------------------------------------------------------
// Generic weight swizzle: W [N][K] f32 -> bf16 frag-block order.
// out[((k32*(N/16)+t)*64+l)*8+j] = W[16t+(l&15)][32*k32+8*(l>>4)+j]
// ---------------------------------------------------------------------------
__global__ void swz_kernel(const float* __restrict__ W, unsigned short* __restrict__ out,
                           int N, int K) {
  int tid = blockIdx.x * 256 + threadIdx.x;
  if (tid >= N * K) return;
  int j = tid & 7, l = (tid >> 3) & 63, rest = tid >> 9;
  int nt = N >> 4;
  int t = rest % nt, k32 = rest / nt;
  int o = t * 16 + (l & 15);
  int k = k32 * 32 + (l >> 4) * 8 + j;
  out[tid] = (unsigned short)bf16_rne(W[(size_t)o * K + k]);
}

// ---------------------------------------------------------------------------
// Layer-0 symmetrized pair enumeration: for m = 0..39, octets n0 = 8*(m/8)..32.
// 120 octets total (K=960). tbl0[g] = m | (n0 << 8).
// ---------------------------------------------------------------------------
__global__ void tbl_kernel(u32* __restrict__ tbl0) {
  int g = threadIdx.x;
  if (g >= 120) return;
  int base = 0, m = 0;
  for (m = 0; m < 40; ++m) {
    int cnt = 5 - (m >> 3);
    if (g < base + cnt) break;
    base += cnt;
  }
  int n0 = 8 * ((m >> 3) + (g - base));
  tbl0[g] = (u32)m | ((u32)n0 << 8);
}

// Symmetrized layer-0 weights in frag order, K = 960 (N=128 -> nt=8).
// val = 0 if n<m; w[m,m] if n==m; w[m,n]+w[n,m] if n>m.
__global__ void swz0s_kernel(const float* __restrict__ W, const u32* __restrict__ tbl0,
                             unsigned short* __restrict__ out) {
  int tid = blockIdx.x * 256 + threadIdx.x;
  if (tid >= 960 * 128) return;
  int j = tid & 7, l = (tid >> 3) & 63, rest = tid >> 9;
  int t = rest & 7, k32 = rest >> 3;
  int o = t * 16 + (l & 15);
  int g = k32 * 4 + (l >> 4);
  u32 te = tbl0[g];
  int m = (int)(te & 255u), n0 = (int)(te >> 8);
  int n = n0 + j;
  float val;
  if (n < m) val = 0.f;
  else if (n == m) val = W[o * 1600 + m * 41];
  else val = W[o * 1600 + m * 40 + n] + W[o * 1600 + n * 40 + m];
  out[tid] = (unsigned short)bf16_rne(val);
}

// ---------------------------------------------------------------------------
__global__ void lin_kernel(const float* __restrict__ x, const float* __restrict__ lw,
                           const float* __restrict__ lb, const float* __restrict__ cb,
                           float* __restrict__ aux) {
  int row = blockIdx.x * 4 + (threadIdx.x >> 6);
  int lane = threadIdx.x & 63;
  const float* xr = x + (size_t)row * 1280;
  float s = 0.f;
#pragma unroll
  for (int e = 0; e < 20; ++e) s += xr[e * 64 + lane] * lw[e * 64 + lane];
#pragma unroll
  for (int m = 1; m < 64; m <<= 1) s += __shfl_xor(s, m, 64);
  if (lane == 0) aux[row] = s + lb[0] + cb[0];
}

// ---------------------------------------------------------------------------
// CIN kernel, R4 structure: barrier-free K-loop.
//   Xt  : f32 [r=(b*32+d)][m], stride 40 words (bank-uniform octet reads)
//   h1w : bf16 [r][n], stride 36 u32 words (72 u16)
//   A-frags computed in registers per lane; B-frags global->VGPR, 2-chunk pipe.
// ---------------------------------------------------------------------------
__global__ __launch_bounds__(256, 3) void cin_kernel(
    const float* __restrict__ emb, const unsigned short* __restrict__ wz0s,
    const unsigned short* __restrict__ wz1, const u32* __restrict__ tbl0,
    const float* __restrict__ b0v, const float* __restrict__ b1v,
    const float* __restrict__ cw, float* __restrict__ aux) {
  __shared__ float Xt[4 * 32 * 40];   // 20 KB
  __shared__ u32 h1w[128 * 36];       // 18 KB
  __shared__ u32 tbl[120];
  __shared__ float auxacc[128];

  const int tid = threadIdx.x;
  const int lane = tid & 63;
  const int w = tid >> 6;
  const int wr = w >> 1, wc = w & 1;
  const int rl = lane & 15, q = lane >> 4;
  const int b0blk = blockIdx.x * 4;

  // stage emb -> Xt (transpose [b][m][d] -> [(b*32+d)][m]); 1280 float4 granules
#pragma unroll
  for (int i = 0; i < 5; ++i) {
    int idx = i * 256 + tid;
    {
      int b = idx / 320;
      int rem = idx - b * 320;
      int m = rem >> 3, d0 = (rem & 7) * 4;
      float4 v = *(const float4*)(emb + ((size_t)(b0blk + b) * 40 + m) * 32 + d0);
      float* xc = &Xt[(b * 32 + d0) * 40 + m];
      xc[0] = v.x; xc[40] = v.y; xc[80] = v.z; xc[120] = v.w;
    }
  }
  if (tid < 128) auxacc[tid] = 0.f;
  if (tid < 120) tbl[tid] = tbl0[tid];
  __syncthreads();

  f32x4 acc[4][4];
#pragma unroll
  for (int u = 0; u < 4; ++u)
#pragma unroll
    for (int t = 0; t < 4; ++t) acc[u][t] = f32x4{0.f, 0.f, 0.f, 0.f};

  // ---- layer 0: K=960, 30 chunks, no barriers ----
  {
    const u32* bptr = (const u32*)wz0s + wc * 1024 + lane * 4;
    uint4 bA[4], bB[4];
#pragma unroll
    for (int tt = 0; tt < 4; ++tt) bA[tt] = *(const uint4*)(bptr + tt * 256);

    auto chunk0 = [&](int kc, uint4* bv) {
      u32 te = tbl[kc * 4 + q];
      int mm = (int)(te & 255u);
      int n0 = (int)(te >> 8);
#pragma unroll
      for (int u = 0; u < 4; ++u) {
        int r = 64 * wr + 16 * u + rl;
        const float* xr = &Xt[r * 40];
        float4 v0 = *(const float4*)&xr[n0];
        float4 v1 = *(const float4*)&xr[n0 + 4];
        float xm = xr[mm];
        uint4 afu;
        afu.x = pk_bf16(xm * v0.x, xm * v0.y);
        afu.y = pk_bf16(xm * v0.z, xm * v0.w);
        afu.z = pk_bf16(xm * v1.x, xm * v1.y);
        afu.w = pk_bf16(xm * v1.z, xm * v1.w);
        short8 af = __builtin_bit_cast(short8, afu);
#pragma unroll
        for (int tt = 0; tt < 4; ++tt)
          acc[u][tt] = __builtin_amdgcn_mfma_f32_16x16x32_bf16(
              af, __builtin_bit_cast(short8, bv[tt]), acc[u][tt], 0, 0, 0);
      }
    };

    for (int kc = 0; kc < 30; kc += 2) {
#pragma unroll
      for (int tt = 0; tt < 4; ++tt)
        bB[tt] = *(const uint4*)(bptr + (kc + 1) * 2048 + tt * 256);
      chunk0(kc, bA);
      int kn2 = (kc + 2 < 30) ? kc + 2 : 0;
#pragma unroll
      for (int tt = 0; tt < 4; ++tt)
        bA[tt] = *(const uint4*)(bptr + kn2 * 2048 + tt * 256);
      chunk0(kc + 1, bB);
    }
  }

  // ---- layer-0 epilogue: ch<64 -> h1w (transposed bf16); ch>=64 -> aux ----
  if (wc == 0) {
    unsigned short* h1s = (unsigned short*)h1w;
#pragma unroll
    for (int u = 0; u < 4; ++u) {
      int r0q = 64 * wr + 16 * u + 4 * q;
#pragma unroll
      for (int tt = 0; tt < 4; ++tt) {
        int o = 16 * tt + rl;
        float bb = b0v[o];
#pragma unroll
        for (int i = 0; i < 4; ++i) {
          float vv = fmaxf(acc[u][tt][i] + bb, 0.f);
          h1s[(r0q + i) * 72 + o] = (unsigned short)bf16_rne(vv);
        }
      }
    }
  } else {
#pragma unroll
    for (int u = 0; u < 4; ++u)
#pragma unroll
      for (int i = 0; i < 4; ++i) {
        float sle = 0.f;
#pragma unroll
        for (int tt = 0; tt < 4; ++tt) {
          int o = 64 + 16 * tt + rl;
          sle += fmaxf(acc[u][tt][i] + b0v[o], 0.f) * cw[o - 64];
        }
        sle += __shfl_xor(sle, 1, 16);
        sle += __shfl_xor(sle, 2, 16);
        sle += __shfl_xor(sle, 4, 16);
        sle += __shfl_xor(sle, 8, 16);
        if (rl == 0) atomicAdd(&auxacc[64 * wr + 16 * u + 4 * q + i], sle);
      }
  }
#pragma unroll
  for (int u = 0; u < 4; ++u)
#pragma unroll
    for (int t = 0; t < 4; ++t) acc[u][t] = f32x4{0.f, 0.f, 0.f, 0.f};
  __syncthreads();  // h1w ready

  // ---- layer 1: K=2560, 80 chunks, no barriers ----
  {
    const u32* bptr = (const u32*)wz1 + wc * 1024 + lane * 4;
    uint4 bA[4], bB[4];
#pragma unroll
    for (int tt = 0; tt < 4; ++tt) bA[tt] = *(const uint4*)(bptr + tt * 256);

    auto chunk1 = [&](int kc, uint4* bv) {
      int mm = kc >> 1;
      int wof = ((kc & 1) << 4) + 4 * q;
#pragma unroll
      for (int u = 0; u < 4; ++u) {
        int r = 64 * wr + 16 * u + rl;
        uint4 hp = *(const uint4*)&h1w[r * 36 + wof];
        float hv[8];
        unpack8(hp, hv);
        float xm = Xt[r * 40 + mm];
        uint4 afu;
        afu.x = pk_bf16(xm * hv[0], xm * hv[1]);
        afu.y = pk_bf16(xm * hv[2], xm * hv[3]);
        afu.z = pk_bf16(xm * hv[4], xm * hv[5]);
        afu.w = pk_bf16(xm * hv[6], xm * hv[7]);
        short8 af = __builtin_bit_cast(short8, afu);
#pragma unroll
        for (int tt = 0; tt < 4; ++tt)
          acc[u][tt] = __builtin_amdgcn_mfma_f32_16x16x32_bf16(
              af, __builtin_bit_cast(short8, bv[tt]), acc[u][tt], 0, 0, 0);
      }
    };

    for (int kc = 0; kc < 80; kc += 2) {
#pragma unroll
      for (int tt = 0; tt < 4; ++tt)
        bB[tt] = *(const uint4*)(bptr + (kc + 1) * 2048 + tt * 256);
      chunk1(kc, bA);
      int kn2 = (kc + 2 < 80) ? kc + 2 : 0;
#pragma unroll
      for (int tt = 0; tt < 4; ++tt)
        bA[tt] = *(const uint4*)(bptr + kn2 * 2048 + tt * 256);
      chunk1(kc + 1, bB);
    }
  }

  // ---- layer-1 epilogue ----
#pragma unroll
  for (int u = 0; u < 4; ++u)
#pragma unroll
    for (int i = 0; i < 4; ++i) {
      float sle = 0.f;
#pragma unroll
      for (int tt = 0; tt < 4; ++tt) {
        int o = 64 * wc + 16 * tt + rl;
        sle += fmaxf(acc[u][tt][i] + b1v[o], 0.f) * cw[64 + o];
      }
      sle += __shfl_xor(sle, 1, 16);
      sle += __shfl_xor(sle, 2, 16);
      sle += __shfl_xor(sle, 4, 16);
      sle += __shfl_xor(sle, 8, 16);
      if (rl == 0) atomicAdd(&auxacc[64 * wr + 16 * u + 4 * q + i], sle);
    }
  __syncthreads();
  if (tid < 4) {
    float ssum = 0.f;
    for (int d = 0; d < 32; ++d) ssum += auxacc[tid * 32 + d];
    aux[b0blk + tid] += ssum;  // lin_kernel ran first
  }
}

// ---------------------------------------------------------------------------
// Deep tower GEMM (unchanged from R3).
// ---------------------------------------------------------------------------
template <int NT, bool AF32>
__global__ __launch_bounds__(256, 2) void gemm_deep(
    const void* __restrict__ Ain, const unsigned short* __restrict__ Bswz,
    const float* __restrict__ bias, float* __restrict__ Cout, int M, int N, int K) {
  __shared__ unsigned short At[128 * 40];
  __shared__ u32 Bt[NT * 256];
  const int tid = threadIdx.x, lane = tid & 63, w = tid >> 6;
  const int wr = w >> 1, wc = w & 1, rl = lane & 15, q = lane >> 4;
  const int r0 = blockIdx.x * 128, c0 = blockIdx.y * (NT * 16);
  const int ntg = N >> 4;
  constexpr int WT = NT / 2;
  f32x4 acc[4][WT];
#pragma unroll
  for (int u = 0; u < 4; ++u)
#pragma unroll
    for (int t = 0; t < WT; ++t) acc[u][t] = f32x4{0.f, 0.f, 0.f, 0.f};

  for (int kk = 0; kk < K; kk += 32) {
    __syncthreads();
    {
      int r = tid >> 1, kh = (tid & 1) * 16;
      if constexpr (AF32) {
        const float* A = (const float*)Ain;
        const float* src = A + (size_t)(r0 + r) * K + kk + kh;
        float4 v0 = *(const float4*)src;
        float4 v1 = *(const float4*)(src + 4);
        float4 v2 = *(const float4*)(src + 8);
        float4 v3 = *(const float4*)(src + 12);
        uint4 p0, p1;
        p0.x = pk_bf16(v0.x, v0.y); p0.y = pk_bf16(v0.z, v0.w);
        p0.z = pk_bf16(v1.x, v1.y); p0.w = pk_bf16(v1.z, v1.w);
        p1.x = pk_bf16(v2.x, v2.y); p1.y = pk_bf16(v2.z, v2.w);
        p1.z = pk_bf16(v3.x, v3.y); p1.w = pk_bf16(v3.z, v3.w);
        uint4* dst = (uint4*)&At[r * 40 + kh];
        dst[0] = p0;
        dst[1] = p1;
      } else {
        const unsigned short* A = (const unsigned short*)Ain;
        const uint4* src = (const uint4*)(A + (size_t)(r0 + r) * K + kk + kh);
        uint4* dst = (uint4*)&At[r * 40 + kh];
        dst[0] = src[0];
        dst[1] = src[1];
      }
      const u32* gb = (const u32*)Bswz + ((size_t)(kk >> 5) * ntg + (c0 >> 4)) * 256;
      constexpr int WW = NT * 64;
#pragma unroll
      for (int j = 0; j < NT / 4; ++j)
        glds16(gb + w * WW + j * 256 + lane * 4, &Bt[w * WW + j * 256]);
    }
    __syncthreads();
    short8 af[4];
#pragma unroll
    for (int u = 0; u < 4; ++u) {
      int rt = 4 * wr + u;
      uint4 av = *(const uint4*)&At[(16 * rt + rl) * 40 + q * 8];
      af[u] = __builtin_bit_cast(short8, av);
    }
#pragma unroll
    for (int tt = 0; tt < WT; ++tt) {
      int tg = WT * wc + tt;
      uint4 bv = *(const uint4*)&Bt[(tg * 64 + lane) * 4];
      short8 bfv = __builtin_bit_cast(short8, bv);
#pragma unroll
      for (int u = 0; u < 4; ++u)
        acc[u][tt] = __builtin_amdgcn_mfma_f32_16x16x32_bf16(af[u], bfv, acc[u][tt], 0, 0, 0);
    }
  }
#pragma unroll
  for (int u = 0; u < 4; ++u) {
    int rr = r0 + 64 * wr + 16 * u + 4 * q;
#pragma unroll
    for (int tt = 0; tt < WT; ++tt) {
      int o = c0 + (WT * wc + tt) * 16 + rl;
      float bb = bias[o];
#pragma unroll
      for (int i = 0; i < 4; ++i)
        Cout[(size_t)(rr + i) * N + o] = acc[u][tt][i] + bb;
    }
  }
}

// ---------------------------------------------------------------------------
template <int D, bool OUTF32>
__global__ void ln_relu_kernel(const float* __restrict__ in, const float* __restrict__ g,
                               const float* __restrict__ bt, void* __restrict__ out) {
  int row = blockIdx.x * 4 + (threadIdx.x >> 6);
  int lane = threadIdx.x & 63;
  constexpr int E = D / 64;
  const float* src = in + (size_t)row * D;
  float v[E], s1 = 0.f, s2 = 0.f;
#pragma unroll
  for (int e = 0; e < E; ++e) {
    v[e] = src[e * 64 + lane];
    s1 += v[e];
    s2 += v[e] * v[e];
  }
#pragma unroll
  for (int m = 1; m < 64; m <<= 1) {
    s1 += __shfl_xor(s1, m, 64);
    s2 += __shfl_xor(s2, m, 64);
  }
  float mu = s1 / (float)D;
  float rs = rsqrtf(s2 / (float)D - mu * mu + 1e-5f);
#pragma unroll
  for (int e = 0; e < E; ++e) {
    int c = e * 64 + lane;
    float y = fmaxf((v[e] - mu) * rs * g[c] + bt[c], 0.f);
    if constexpr (OUTF32)
      ((float*)out)[(size_t)row * D + c] = y;
    else
      ((unsigned short*)out)[(size_t)row * D + c] = (unsigned short)bf16_rne(y);
  }
}

// ---------------------------------------------------------------------------
extern "C" void kernel_launch(void* const* d_in, const int* in_sizes, int n_in,
                              void* d_out, int out_size, void* d_ws, size_t ws_size,
                              hipStream_t stream) {
  const float* x = (const float*)d_in[0];
  const float* emb = (const float*)d_in[1];
  const float* lin_w = (const float*)d_in[2];
  const float* lin_b = (const float*)d_in[3];
  const float* cw0 = (const float*)d_in[4];
  const float* cb0 = (const float*)d_in[5];
  const float* cw1 = (const float*)d_in[6];
  const float* cb1 = (const float*)d_in[7];
  const float* cow = (const float*)d_in[8];
  const float* cob = (const float*)d_in[9];
  const float* dw0 = (const float*)d_in[10];
  const float* db0 = (const float*)d_in[11];
  const float* g0 = (const float*)d_in[12];
  const float* be0 = (const float*)d_in[13];
  const float* dw1 = (const float*)d_in[14];
  const float* db1 = (const float*)d_in[15];
  const float* g1 = (const float*)d_in[16];
  const float* be1 = (const float*)d_in[17];
  const float* dw2 = (const float*)d_in[18];
  const float* db2 = (const float*)d_in[19];
  const float* g2 = (const float*)d_in[20];
  const float* be2 = (const float*)d_in[21];

  char* ws = (char*)d_ws;
  unsigned short* wz0s = (unsigned short*)(ws + 0);        // 245760
  u32* tbl0 = (u32*)(ws + 245760);                         // 512
  unsigned short* wz1 = (unsigned short*)(ws + 246272);    // 655360
  unsigned short* wzd0 = (unsigned short*)(ws + 901632);   // 655360
  unsigned short* wzd1 = (unsigned short*)(ws + 1556992);  // 65536
  unsigned short* wzd2 = (unsigned short*)(ws + 1622528);  // 16384
  float* t0 = (float*)(ws + 1638912);                      // 16777216
  unsigned short* h0b = (unsigned short*)(ws + 18416128);  // 8388608
  float* t1 = (float*)(ws + 26804736);                     // 8388608
  unsigned short* h1b = (unsigned short*)(ws + 35193344);  // 4194304
  float* t2 = (float*)(ws + 39387648);                     // 4194304 (tot 43.6MB)

  float* h_out = (float*)d_out;
  float* aux = h_out + (size_t)16384 * 64;

  tbl_kernel<<<1, 128, 0, stream>>>(tbl0);
  swz0s_kernel<<<480, 256, 0, stream>>>(cw0, tbl0, wz0s);
  swz_kernel<<<(2560 * 128 + 255) / 256, 256, 0, stream>>>(cw1, wz1, 128, 2560);
  swz_kernel<<<(1280 * 256 + 255) / 256, 256, 0, stream>>>(dw0, wzd0, 256, 1280);
  swz_kernel<<<(256 * 128 + 255) / 256, 256, 0, stream>>>(dw1, wzd1, 128, 256);
  swz_kernel<<<(128 * 64 + 255) / 256, 256, 0, stream>>>(dw2, wzd2, 64, 128);

  lin_kernel<<<4096, 256, 0, stream>>>(x, lin_w, lin_b, cob, aux);
  cin_kernel<<<4096, 256, 0, stream>>>(emb, wz0s, wz1, tbl0, cb0, cb1, cow, aux);

  gemm_deep<8, true><<<dim3(128, 2), 256, 0, stream>>>(x, wzd0, db0, t0, 16384, 256, 1280);
  ln_relu_kernel<256, false><<<4096, 256, 0, stream>>>(t0, g0, be0, h0b);
  gemm_deep<8, false><<<dim3(128, 1), 256, 0, stream>>>(h0b, wzd1, db1, t1, 16384, 128, 256);
  ln_relu_kernel<128, false><<<4096, 256, 0, stream>>>(t1, g1, be1, h1b);
  gemm_deep<4, false><<<dim3(128, 1), 256, 0, stream>>>(h1b, wzd2, db2, t2, 16384, 64, 128);
  ln_relu_kernel<64, true><<<4096, 256, 0, stream>>>(t2, g2, be2, h_out);
}

// Round 6
// 728.201 us; speedup vs baseline: 1.6888x; 1.0675x over previous
//
#include <hip/hip_runtime.h>
#include <hip/hip_bf16.h>

typedef unsigned int u32;
typedef __attribute__((ext_vector_type(8))) short short8;
typedef __attribute__((ext_vector_type(8))) _Float16 half8;
typedef __attribute__((ext_vector_type(4))) float f32x4;

__device__ __forceinline__ u32 bf16_rne(float f) {
  u32 u = __builtin_bit_cast(u32, f);
  return (u + 0x7fffu + ((u >> 16) & 1u)) >> 16;
}
__device__ __forceinline__ u32 pk_bf16(float a, float b) {
  union { __hip_bfloat162 h; u32 u; } cv;
  cv.h = __float22bfloat162_rn(make_float2(a, b));
  return cv.u;
}
__device__ __forceinline__ unsigned short f16b(float f) {
  return __builtin_bit_cast(unsigned short, (_Float16)f);
}
__device__ __forceinline__ half8 splat8(_Float16 x) {
  return (half8){x, x, x, x, x, x, x, x};
}

__device__ __forceinline__ void glds16(const u32* g, u32* l) {
  __builtin_amdgcn_global_load_lds((const __attribute__((address_space(1))) u32*)g,
                                   (__attribute__((address_space(3))) u32*)l, 16, 0, 0);
}

// ---------------------------------------------------------------------------
// Weight swizzles: W [N][K] f32 -> frag-block order. bf16 (deep) / f16 (cin).
// out[((k32*(N/16)+t)*64+l)*8+j] = W[16t+(l&15)][32*k32+8*(l>>4)+j]
// ---------------------------------------------------------------------------
__global__ void swz_kernel(const float* __restrict__ W, unsigned short* __restrict__ out,
                           int N, int K) {
  int tid = blockIdx.x * 256 + threadIdx.x;
  if (tid >= N * K) return;
  int j = tid & 7, l = (tid >> 3) & 63, rest = tid >> 9;
  int nt = N >> 4;
  int t = rest % nt, k32 = rest / nt;
  int o = t * 16 + (l & 15);
  int k = k32 * 32 + (l >> 4) * 8 + j;
  out[tid] = (unsigned short)bf16_rne(W[(size_t)o * K + k]);
}
__global__ void swz_f16_kernel(const float* __restrict__ W, unsigned short* __restrict__ out,
                               int N, int K) {
  int tid = blockIdx.x * 256 + threadIdx.x;
  if (tid >= N * K) return;
  int j = tid & 7, l = (tid >> 3) & 63, rest = tid >> 9;
  int nt = N >> 4;
  int t = rest % nt, k32 = rest / nt;
  int o = t * 16 + (l & 15);
  int k = k32 * 32 + (l >> 4) * 8 + j;
  out[tid] = f16b(W[(size_t)o * K + k]);
}

// ---------------------------------------------------------------------------
// Layer-0 symmetrized pair table: m=0..39, octets n0 = 8*(m/8)..32; 120 entries.
// ---------------------------------------------------------------------------
__global__ void tbl_kernel(u32* __restrict__ tbl0) {
  int g = threadIdx.x;
  if (g >= 120) return;
  int base = 0, m = 0;
  for (m = 0; m < 40; ++m) {
    int cnt = 5 - (m >> 3);
    if (g < base + cnt) break;
    base += cnt;
  }
  int n0 = 8 * ((m >> 3) + (g - base));
  tbl0[g] = (u32)m | ((u32)n0 << 8);
}

// Symmetrized layer-0 weights, f16 frag order, K=960.
__global__ void swz0s_kernel(const float* __restrict__ W, const u32* __restrict__ tbl0,
                             unsigned short* __restrict__ out) {
  int tid = blockIdx.x * 256 + threadIdx.x;
  if (tid >= 960 * 128) return;
  int j = tid & 7, l = (tid >> 3) & 63, rest = tid >> 9;
  int t = rest & 7, k32 = rest >> 3;
  int o = t * 16 + (l & 15);
  int g = k32 * 4 + (l >> 4);
  u32 te = tbl0[g];
  int m = (int)(te & 255u), n0 = (int)(te >> 8);
  int n = n0 + j;
  float val;
  if (n < m) val = 0.f;
  else if (n == m) val = W[o * 1600 + m * 41];
  else val = W[o * 1600 + m * 40 + n] + W[o * 1600 + n * 40 + m];
  out[tid] = f16b(val);
}

// ---------------------------------------------------------------------------
__global__ void lin_kernel(const float* __restrict__ x, const float* __restrict__ lw,
                           const float* __restrict__ lb, const float* __restrict__ cb,
                           float* __restrict__ aux) {
  int row = blockIdx.x * 4 + (threadIdx.x >> 6);
  int lane = threadIdx.x & 63;
  const float* xr = x + (size_t)row * 1280;
  float s = 0.f;
#pragma unroll
  for (int e = 0; e < 20; ++e) s += xr[e * 64 + lane] * lw[e * 64 + lane];
#pragma unroll
  for (int m = 1; m < 64; m <<= 1) s += __shfl_xor(s, m, 64);
  if (lane == 0) aux[row] = s + lb[0] + cb[0];
}

// ---------------------------------------------------------------------------
// CIN kernel, fp16 A-path. Barrier-free K-loops, register B double-buffer.
//   Xh  : f16 [r=(b*32+d)][m], row stride 44 halfs (22 words)
//   h1s : f16 [r][n], row stride 68 halfs (34 words)
// A-frag = packed v_pk_mul_f16 of xm-splat with n/h1 octet.
// ---------------------------------------------------------------------------
__global__ __launch_bounds__(256, 4) void cin_kernel(
    const float* __restrict__ emb, const unsigned short* __restrict__ wz0s,
    const unsigned short* __restrict__ wz1, const u32* __restrict__ tbl0,
    const float* __restrict__ b0v, const float* __restrict__ b1v,
    const float* __restrict__ cw, float* __restrict__ aux) {
  __shared__ unsigned short Xh[128 * 44];   // 11.3 KB
  __shared__ unsigned short h1s[128 * 68];  // 17.4 KB
  __shared__ u32 tbl[120];
  __shared__ float auxacc[128];

  const int tid = threadIdx.x;
  const int lane = tid & 63;
  const int w = tid >> 6;
  const int wr = w >> 1, wc = w & 1;
  const int rl = lane & 15, q = lane >> 4;
  const int b0blk = blockIdx.x * 4;

  // stage emb -> Xh (transpose [b][m][d] -> [(b*32+d)][m], f16)
#pragma unroll
  for (int i = 0; i < 5; ++i) {
    int idx = i * 256 + tid;
    int b = idx / 320;
    int rem = idx - b * 320;
    int m = rem >> 3, d0 = (rem & 7) * 4;
    float4 v = *(const float4*)(emb + ((size_t)(b0blk + b) * 40 + m) * 32 + d0);
    unsigned short* xc = &Xh[(b * 32 + d0) * 44 + m];
    xc[0] = f16b(v.x); xc[44] = f16b(v.y); xc[88] = f16b(v.z); xc[132] = f16b(v.w);
  }
  if (tid < 128) auxacc[tid] = 0.f;
  if (tid < 120) tbl[tid] = tbl0[tid];
  __syncthreads();

  f32x4 acc[4][4];
#pragma unroll
  for (int u = 0; u < 4; ++u)
#pragma unroll
    for (int t = 0; t < 4; ++t) acc[u][t] = f32x4{0.f, 0.f, 0.f, 0.f};

  // ---- layer 0: K=960, 30 chunks ----
  {
    const u32* bptr = (const u32*)wz0s + wc * 1024 + lane * 4;
    uint4 bA[4], bB[4];
#pragma unroll
    for (int tt = 0; tt < 4; ++tt) bA[tt] = *(const uint4*)(bptr + tt * 256);

    auto chunk0 = [&](int kc, uint4* bv) {
      u32 te = tbl[kc * 4 + q];
      int mm = (int)(te & 255u);
      int w0 = (int)(te >> 8) >> 1;  // word offset of n-octet
#pragma unroll
      for (int u = 0; u < 4; ++u) {
        int r = 64 * wr + 16 * u + rl;
        const u32* xr = (const u32*)&Xh[r * 44];
        uint4 vn = *(const uint4*)&xr[w0];
        _Float16 xm = __builtin_bit_cast(_Float16, Xh[r * 44 + mm]);
        half8 af = __builtin_bit_cast(half8, vn) * splat8(xm);
#pragma unroll
        for (int tt = 0; tt < 4; ++tt)
          acc[u][tt] = __builtin_amdgcn_mfma_f32_16x16x32_f16(
              af, __builtin_bit_cast(half8, bv[tt]), acc[u][tt], 0, 0, 0);
      }
    };

    for (int kc = 0; kc < 30; kc += 2) {
#pragma unroll
      for (int tt = 0; tt < 4; ++tt)
        bB[tt] = *(const uint4*)(bptr + (kc + 1) * 2048 + tt * 256);
      chunk0(kc, bA);
      int kn2 = (kc + 2 < 30) ? kc + 2 : 0;
#pragma unroll
      for (int tt = 0; tt < 4; ++tt)
        bA[tt] = *(const uint4*)(bptr + kn2 * 2048 + tt * 256);
      chunk0(kc + 1, bB);
    }
  }

  // ---- layer-0 epilogue: ch<64 -> h1s (f16); ch>=64 -> aux partial ----
  if (wc == 0) {
#pragma unroll
    for (int u = 0; u < 4; ++u) {
      int r0q = 64 * wr + 16 * u + 4 * q;
#pragma unroll
      for (int tt = 0; tt < 4; ++tt) {
        int o = 16 * tt + rl;
        float bb = b0v[o];
#pragma unroll
        for (int i = 0; i < 4; ++i) {
          float vv = fmaxf(acc[u][tt][i] + bb, 0.f);
          h1s[(r0q + i) * 68 + o] = f16b(vv);
        }
      }
    }
  } else {
#pragma unroll
    for (int u = 0; u < 4; ++u)
#pragma unroll
      for (int i = 0; i < 4; ++i) {
        float sle = 0.f;
#pragma unroll
        for (int tt = 0; tt < 4; ++tt) {
          int o = 64 + 16 * tt + rl;
          sle += fmaxf(acc[u][tt][i] + b0v[o], 0.f) * cw[o - 64];
        }
        sle += __shfl_xor(sle, 1, 16);
        sle += __shfl_xor(sle, 2, 16);
        sle += __shfl_xor(sle, 4, 16);
        sle += __shfl_xor(sle, 8, 16);
        if (rl == 0) atomicAdd(&auxacc[64 * wr + 16 * u + 4 * q + i], sle);
      }
  }
#pragma unroll
  for (int u = 0; u < 4; ++u)
#pragma unroll
    for (int t = 0; t < 4; ++t) acc[u][t] = f32x4{0.f, 0.f, 0.f, 0.f};
  __syncthreads();  // h1s ready

  // ---- layer 1: K=2560, 80 chunks ----
  {
    const u32* bptr = (const u32*)wz1 + wc * 1024 + lane * 4;
    uint4 bA[4], bB[4];
#pragma unroll
    for (int tt = 0; tt < 4; ++tt) bA[tt] = *(const uint4*)(bptr + tt * 256);

    auto chunk1 = [&](int kc, uint4* bv) {
      int mm = kc >> 1;
      int wof = ((kc & 1) << 4) + 4 * q;  // word offset into h1 row
#pragma unroll
      for (int u = 0; u < 4; ++u) {
        int r = 64 * wr + 16 * u + rl;
        uint4 hp = *(const uint4*)((const u32*)h1s + r * 34 + wof);
        _Float16 xm = __builtin_bit_cast(_Float16, Xh[r * 44 + mm]);
        half8 af = __builtin_bit_cast(half8, hp) * splat8(xm);
#pragma unroll
        for (int tt = 0; tt < 4; ++tt)
          acc[u][tt] = __builtin_amdgcn_mfma_f32_16x16x32_f16(
              af, __builtin_bit_cast(half8, bv[tt]), acc[u][tt], 0, 0, 0);
      }
    };

    for (int kc = 0; kc < 80; kc += 2) {
#pragma unroll
      for (int tt = 0; tt < 4; ++tt)
        bB[tt] = *(const uint4*)(bptr + (kc + 1) * 2048 + tt * 256);
      chunk1(kc, bA);
      int kn2 = (kc + 2 < 80) ? kc + 2 : 0;
#pragma unroll
      for (int tt = 0; tt < 4; ++tt)
        bA[tt] = *(const uint4*)(bptr + kn2 * 2048 + tt * 256);
      chunk1(kc + 1, bB);
    }
  }

  // ---- layer-1 epilogue ----
#pragma unroll
  for (int u = 0; u < 4; ++u)
#pragma unroll
    for (int i = 0; i < 4; ++i) {
      float sle = 0.f;
#pragma unroll
      for (int tt = 0; tt < 4; ++tt) {
        int o = 64 * wc + 16 * tt + rl;
        sle += fmaxf(acc[u][tt][i] + b1v[o], 0.f) * cw[64 + o];
      }
      sle += __shfl_xor(sle, 1, 16);
      sle += __shfl_xor(sle, 2, 16);
      sle += __shfl_xor(sle, 4, 16);
      sle += __shfl_xor(sle, 8, 16);
      if (rl == 0) atomicAdd(&auxacc[64 * wr + 16 * u + 4 * q + i], sle);
    }
  __syncthreads();
  if (tid < 4) {
    float ssum = 0.f;
    for (int d = 0; d < 32; ++d) ssum += auxacc[tid * 32 + d];
    aux[b0blk + tid] += ssum;  // lin_kernel ran first
  }
}

// ---------------------------------------------------------------------------
// Deep tower GEMM (bf16, unchanged).
// ---------------------------------------------------------------------------
template <int NT, bool AF32>
__global__ __launch_bounds__(256, 2) void gemm_deep(
    const void* __restrict__ Ain, const unsigned short* __restrict__ Bswz,
    const float* __restrict__ bias, float* __restrict__ Cout, int M, int N, int K) {
  __shared__ unsigned short At[128 * 40];
  __shared__ u32 Bt[NT * 256];
  const int tid = threadIdx.x, lane = tid & 63, w = tid >> 6;
  const int wr = w >> 1, wc = w & 1, rl = lane & 15, q = lane >> 4;
  const int r0 = blockIdx.x * 128, c0 = blockIdx.y * (NT * 16);
  const int ntg = N >> 4;
  constexpr int WT = NT / 2;
  f32x4 acc[4][WT];
#pragma unroll
  for (int u = 0; u < 4; ++u)
#pragma unroll
    for (int t = 0; t < WT; ++t) acc[u][t] = f32x4{0.f, 0.f, 0.f, 0.f};

  for (int kk = 0; kk < K; kk += 32) {
    __syncthreads();
    {
      int r = tid >> 1, kh = (tid & 1) * 16;
      if constexpr (AF32) {
        const float* A = (const float*)Ain;
        const float* src = A + (size_t)(r0 + r) * K + kk + kh;
        float4 v0 = *(const float4*)src;
        float4 v1 = *(const float4*)(src + 4);
        float4 v2 = *(const float4*)(src + 8);
        float4 v3 = *(const float4*)(src + 12);
        uint4 p0, p1;
        p0.x = pk_bf16(v0.x, v0.y); p0.y = pk_bf16(v0.z, v0.w);
        p0.z = pk_bf16(v1.x, v1.y); p0.w = pk_bf16(v1.z, v1.w);
        p1.x = pk_bf16(v2.x, v2.y); p1.y = pk_bf16(v2.z, v2.w);
        p1.z = pk_bf16(v3.x, v3.y); p1.w = pk_bf16(v3.z, v3.w);
        uint4* dst = (uint4*)&At[r * 40 + kh];
        dst[0] = p0;
        dst[1] = p1;
      } else {
        const unsigned short* A = (const unsigned short*)Ain;
        const uint4* src = (const uint4*)(A + (size_t)(r0 + r) * K + kk + kh);
        uint4* dst = (uint4*)&At[r * 40 + kh];
        dst[0] = src[0];
        dst[1] = src[1];
      }
      const u32* gb = (const u32*)Bswz + ((size_t)(kk >> 5) * ntg + (c0 >> 4)) * 256;
      constexpr int WW = NT * 64;
#pragma unroll
      for (int j = 0; j < NT / 4; ++j)
        glds16(gb + w * WW + j * 256 + lane * 4, &Bt[w * WW + j * 256]);
    }
    __syncthreads();
    short8 af[4];
#pragma unroll
    for (int u = 0; u < 4; ++u) {
      int rt = 4 * wr + u;
      uint4 av = *(const uint4*)&At[(16 * rt + rl) * 40 + q * 8];
      af[u] = __builtin_bit_cast(short8, av);
    }
#pragma unroll
    for (int tt = 0; tt < WT; ++tt) {
      int tg = WT * wc + tt;
      uint4 bv = *(const uint4*)&Bt[(tg * 64 + lane) * 4];
      short8 bfv = __builtin_bit_cast(short8, bv);
#pragma unroll
      for (int u = 0; u < 4; ++u)
        acc[u][tt] = __builtin_amdgcn_mfma_f32_16x16x32_bf16(af[u], bfv, acc[u][tt], 0, 0, 0);
    }
  }
#pragma unroll
  for (int u = 0; u < 4; ++u) {
    int rr = r0 + 64 * wr + 16 * u + 4 * q;
#pragma unroll
    for (int tt = 0; tt < WT; ++tt) {
      int o = c0 + (WT * wc + tt) * 16 + rl;
      float bb = bias[o];
#pragma unroll
      for (int i = 0; i < 4; ++i)
        Cout[(size_t)(rr + i) * N + o] = acc[u][tt][i] + bb;
    }
  }
}

// ---------------------------------------------------------------------------
template <int D, bool OUTF32>
__global__ void ln_relu_kernel(const float* __restrict__ in, const float* __restrict__ g,
                               const float* __restrict__ bt, void* __restrict__ out) {
  int row = blockIdx.x * 4 + (threadIdx.x >> 6);
  int lane = threadIdx.x & 63;
  constexpr int E = D / 64;
  const float* src = in + (size_t)row * D;
  float v[E], s1 = 0.f, s2 = 0.f;
#pragma unroll
  for (int e = 0; e < E; ++e) {
    v[e] = src[e * 64 + lane];
    s1 += v[e];
    s2 += v[e] * v[e];
  }
#pragma unroll
  for (int m = 1; m < 64; m <<= 1) {
    s1 += __shfl_xor(s1, m, 64);
    s2 += __shfl_xor(s2, m, 64);
  }
  float mu = s1 / (float)D;
  float rs = rsqrtf(s2 / (float)D - mu * mu + 1e-5f);
#pragma unroll
  for (int e = 0; e < E; ++e) {
    int c = e * 64 + lane;
    float y = fmaxf((v[e] - mu) * rs * g[c] + bt[c], 0.f);
    if constexpr (OUTF32)
      ((float*)out)[(size_t)row * D + c] = y;
    else
      ((unsigned short*)out)[(size_t)row * D + c] = (unsigned short)bf16_rne(y);
  }
}

// ---------------------------------------------------------------------------
extern "C" void kernel_launch(void* const* d_in, const int* in_sizes, int n_in,
                              void* d_out, int out_size, void* d_ws, size_t ws_size,
                              hipStream_t stream) {
  const float* x = (const float*)d_in[0];
  const float* emb = (const float*)d_in[1];
  const float* lin_w = (const float*)d_in[2];
  const float* lin_b = (const float*)d_in[3];
  const float* cw0 = (const float*)d_in[4];
  const float* cb0 = (const float*)d_in[5];
  const float* cw1 = (const float*)d_in[6];
  const float* cb1 = (const float*)d_in[7];
  const float* cow = (const float*)d_in[8];
  const float* cob = (const float*)d_in[9];
  const float* dw0 = (const float*)d_in[10];
  const float* db0 = (const float*)d_in[11];
  const float* g0 = (const float*)d_in[12];
  const float* be0 = (const float*)d_in[13];
  const float* dw1 = (const float*)d_in[14];
  const float* db1 = (const float*)d_in[15];
  const float* g1 = (const float*)d_in[16];
  const float* be1 = (const float*)d_in[17];
  const float* dw2 = (const float*)d_in[18];
  const float* db2 = (const float*)d_in[19];
  const float* g2 = (const float*)d_in[20];
  const float* be2 = (const float*)d_in[21];

  char* ws = (char*)d_ws;
  unsigned short* wz0s = (unsigned short*)(ws + 0);        // 245760 (f16)
  u32* tbl0 = (u32*)(ws + 245760);                         // 512
  unsigned short* wz1 = (unsigned short*)(ws + 246272);    // 655360 (f16)
  unsigned short* wzd0 = (unsigned short*)(ws + 901632);   // 655360 (bf16)
  unsigned short* wzd1 = (unsigned short*)(ws + 1556992);  // 65536
  unsigned short* wzd2 = (unsigned short*)(ws + 1622528);  // 16384
  float* t0 = (float*)(ws + 1638912);                      // 16777216
  unsigned short* h0b = (unsigned short*)(ws + 18416128);  // 8388608
  float* t1 = (float*)(ws + 26804736);                     // 8388608
  unsigned short* h1b = (unsigned short*)(ws + 35193344);  // 4194304
  float* t2 = (float*)(ws + 39387648);                     // 4194304

  float* h_out = (float*)d_out;
  float* aux = h_out + (size_t)16384 * 64;

  tbl_kernel<<<1, 128, 0, stream>>>(tbl0);
  swz0s_kernel<<<480, 256, 0, stream>>>(cw0, tbl0, wz0s);
  swz_f16_kernel<<<(2560 * 128 + 255) / 256, 256, 0, stream>>>(cw1, wz1, 128, 2560);
  swz_kernel<<<(1280 * 256 + 255) / 256, 256, 0, stream>>>(dw0, wzd0, 256, 1280);
  swz_kernel<<<(256 * 128 + 255) / 256, 256, 0, stream>>>(dw1, wzd1, 128, 256);
  swz_kernel<<<(128 * 64 + 255) / 256, 256, 0, stream>>>(dw2, wzd2, 64, 128);

  lin_kernel<<<4096, 256, 0, stream>>>(x, lin_w, lin_b, cob, aux);
  cin_kernel<<<4096, 256, 0, stream>>>(emb, wz0s, wz1, tbl0, cb0, cb1, cow, aux);

  gemm_deep<8, true><<<dim3(128, 2), 256, 0, stream>>>(x, wzd0, db0, t0, 16384, 256, 1280);
  ln_relu_kernel<256, false><<<4096, 256, 0, stream>>>(t0, g0, be0, h0b);
  gemm_deep<8, false><<<dim3(128, 1), 256, 0, stream>>>(h0b, wzd1, db1, t1, 16384, 128, 256);
  ln_relu_kernel<128, false><<<4096, 256, 0, stream>>>(t1, g1, be1, h1b);
  gemm_deep<4, false><<<dim3(128, 1), 256, 0, stream>>>(h1b, wzd2, db2, t2, 16384, 64, 128);
  ln_relu_kernel<64, true><<<4096, 256, 0, stream>>>(t2, g2, be2, h_out);
}